// Round 14
// baseline (44.907 us; speedup 1.0000x reference)
//
#include <hip/hip_runtime.h>
#include <hip/hip_fp16.h>

#define NROWS 16384
#define NG 100
#define NC 10
#define NH 32
#define NS 10
#define GPC 10
#define SLOPE 0.2f
#define BN_EPS 1e-5f

#define RPB 64             // rows per block (2 rows/thread)
#define BLOCK_A 512        // 32 row-slots * 16 lanes/row
#define NB (NROWS / RPB)   // 256 blocks

// ---- DPP cross-lane adds (VALU pipe; verified rounds 7/8/11/12) ----
template<int CTRL>
__device__ __forceinline__ float dpp_add(float v) {
    int x = __builtin_bit_cast(int, v);
    int y = __builtin_amdgcn_update_dpp(0, x, CTRL, 0xF, 0xF, true);
    return v + __builtin_bit_cast(float, y);
}
__device__ __forceinline__ float row16_allreduce(float v) {
    v = dpp_add<0x128>(v);  // row_ror:8
    v = dpp_add<0x124>(v);  // row_ror:4
    v = dpp_add<0x122>(v);  // row_ror:2
    v = dpp_add<0x121>(v);  // row_ror:1
    return v;
}
// ys UNIFORM within each 16-lane group: lane63 = sum of the wave's 4 groups
__device__ __forceinline__ float uniform16_wavesum_lane63(float v) {
    v = dpp_add<0x142>(v);  // row_bcast15
    v = dpp_add<0x143>(v);  // row_bcast31
    return v;
}

// gather chrom c for one row-stream: ONE ds_read_b64 per gene -> {h:half2, e:f32}
#define GATHER(c, arr, pkv)                                                \
    _Pragma("unroll")                                                      \
    for (int gp = 0; gp < GPC; ++gp) {                                     \
        const int g_ = (c) * GPC + gp;                                     \
        const unsigned xg_ = (pkv[g_ >> 4] >> ((g_ & 15) * 2)) & 3u;       \
        const int r3_ = g_ * 3 + (int)xg_;                                 \
        arr[gp] = cmbL[r3_ * 16 + o];                                      \
    }

#define COMPUTE(arr, num, den) do {                                        \
    float e_[GPC];                                                         \
    _Pragma("unroll")                                                      \
    for (int gp = 0; gp < GPC; ++gp)                                       \
        e_[gp] = __builtin_bit_cast(float, arr[gp].y);                     \
    const float s01_ = (e_[0] + e_[1]) + (e_[2] + e_[3]);                  \
    const float s23_ = (e_[4] + e_[5]) + (e_[6] + e_[7]);                  \
    const float suma_ = (s01_ + s23_) + (e_[8] + e_[9]);                   \
    const float inv_ = 1.f / fmaxf(suma_, 1e-10f);                         \
    float2 chA_ = {0.f, 0.f}, chB_ = {0.f, 0.f};                           \
    _Pragma("unroll")                                                      \
    for (int gp = 0; gp < GPC; gp += 2) {                                  \
        float2 h0_ = __half22float2(__builtin_bit_cast(__half2, arr[gp].x)); \
        float2 h1_ = __half22float2(__builtin_bit_cast(__half2, arr[gp+1].x)); \
        chA_.x = fmaf(e_[gp],   h0_.x, chA_.x);                            \
        chA_.y = fmaf(e_[gp],   h0_.y, chA_.y);                            \
        chB_.x = fmaf(e_[gp+1], h1_.x, chB_.x);                            \
        chB_.y = fmaf(e_[gp+1], h1_.y, chB_.y);                            \
    }                                                                      \
    float2 ch_ = {chA_.x + chB_.x, chA_.y + chB_.y};                       \
    ch_.x = fmaxf(ch_.x, 0.f);  /* ReLU commutes with +ve 1/suma scale */  \
    ch_.y = fmaxf(ch_.y, 0.f);                                             \
    float pc_ = ch_.x * ca.x + ch_.y * ca.y;                               \
    pc_ = row16_allreduce(pc_);                                            \
    pc_ *= inv_;                       /* catt[n][c] */                    \
    const float lc_ = pc_ > 0.f ? pc_ : SLOPE * pc_;                       \
    const float ec_ = __expf(lc_);                                         \
    const float w_ = ec_ * inv_;                                           \
    num.x = fmaf(w_, ch_.x, num.x);                                        \
    num.y = fmaf(w_, ch_.y, num.y);                                        \
    den += ec_;                                                            \
} while (0)

// ================= main kernel: 256 blocks, 2 rows/thread =================
template<bool SLOTS>
__global__ __launch_bounds__(BLOCK_A, 2) void gga_main(
    const int* __restrict__ x, const float* __restrict__ emb,
    const float* __restrict__ gene_att, const float* __restrict__ chrom_att,
    const float* __restrict__ W, const float* __restrict__ b,
    float* __restrict__ y, float* __restrict__ P)
{
    __shared__ uint2 cmbL[300 * 16];   // 38.4 KB: {x = half2 h(2o,2o+1), y = f32 e}
    __shared__ float eL[300];
    __shared__ float WTL[NS * NH];     // WT[s][h]
    __shared__ float bL[NS];
    __shared__ unsigned xpL[RPB * 8];  // 64 rows * 8 packed words
    __shared__ float sAcc[2 * NS];

    const int t = threadIdx.x;
    const int n0 = blockIdx.x * RPB;

    // ---- phase 0 (round-8 ordering) ----
    if (t < 300) {                                     // e-table from global f32 emb
        const int g = t / 3;
        const float* ga = gene_att + (g / GPC) * NH;
        const float* e = emb + t * NH;
        float s = 0.f;
#pragma unroll
        for (int k = 0; k < NH; k += 4) {
            float4 ev = *reinterpret_cast<const float4*>(e + k);
            float4 gv = *reinterpret_cast<const float4*>(ga + k);
            s = fmaf(gv.x, ev.x, s); s = fmaf(gv.y, ev.y, s);
            s = fmaf(gv.z, ev.z, s); s = fmaf(gv.w, ev.w, s);
        }
        const float lk = s > 0.f ? s : SLOPE * s;
        eL[t] = (s != 0.f) ? __expf(lk) : 0.f;
    }
    if (t < NH * NS) WTL[t] = W[(t & 31) * NS + (t >> 5)];   // WT[s][h]
    if (t < NS) bL[t] = b[t];
    if (t < 2 * NS) sAcc[t] = 0.f;
    {   // cooperative x pack: all 512 threads -> 64 rows x 8 words
        const int r = t >> 3, w = t & 7;
        unsigned pw = 0u;
        if (w < 7) {
            const int4* p = reinterpret_cast<const int4*>(x + (n0 + r) * NG + w * 16);
            const int nv = (w < 6) ? 4 : 1;            // word 6: trits 96..99 only
#pragma unroll
            for (int i = 0; i < 4; ++i) {
                if (i < nv) {
                    int4 v = p[i];
                    pw |= ((unsigned)v.x & 3u) << (i * 8 + 0);
                    pw |= ((unsigned)v.y & 3u) << (i * 8 + 2);
                    pw |= ((unsigned)v.z & 3u) << (i * 8 + 4);
                    pw |= ((unsigned)v.w & 3u) << (i * 8 + 6);
                }
            }
        }
        xpL[r * 8 + w] = pw;
    }
    __syncthreads();

    // ---- phase 1: fused {h,e} table (coalesced float2 global reads) ----
#pragma unroll
    for (int i2 = 0; i2 < 10; ++i2) {
        const int i = t + i2 * BLOCK_A;
        if (i < 4800) {                                 // i = r3*16 + o
            float2 hv = reinterpret_cast<const float2*>(emb)[i];
            __half2 h2 = __floats2half2_rn(hv.x, hv.y);
            uint2 en;
            en.x = __builtin_bit_cast(unsigned, h2);
            en.y = __builtin_bit_cast(unsigned, eL[i >> 4]);
            cmbL[i] = en;
        }
    }
    __syncthreads();

    // ---- per-thread: TWO rows (lr, lr+32), 16 lanes/row ----
    const int lr = t >> 4;          // 0..31
    const int o = t & 15;
    const int n = n0 + lr;          // second row: n + 32

    const float2 ca = reinterpret_cast<const float2*>(chrom_att)[o];

    const uint4 pa0 = *reinterpret_cast<const uint4*>(&xpL[lr * 8]);
    const uint4 pb0 = *reinterpret_cast<const uint4*>(&xpL[lr * 8 + 4]);
    const unsigned pk0[8] = {pa0.x, pa0.y, pa0.z, pa0.w, pb0.x, pb0.y, pb0.z, pb0.w};
    const uint4 pa1 = *reinterpret_cast<const uint4*>(&xpL[(lr + 32) * 8]);
    const uint4 pb1 = *reinterpret_cast<const uint4*>(&xpL[(lr + 32) * 8 + 4]);
    const unsigned pk1[8] = {pa1.x, pa1.y, pa1.z, pa1.w, pb1.x, pb1.y, pb1.z, pb1.w};

    float2 num0 = {0.f, 0.f}, num1 = {0.f, 0.f};
    float den0 = 0.f, den1 = 0.f;

    // dual-stream: 20 independent ds_read_b64 issued per c before the 2 computes
    uint2 a0[GPC], a1[GPC];
#pragma unroll
    for (int c = 0; c < NC; ++c) {
        GATHER(c, a0, pk0);
        GATHER(c, a1, pk1);
        COMPUTE(a0, num0, den0);
        COMPUTE(a1, num1, den1);
    }

    const float invd0 = 1.f / den0;
    const float ga0 = fmaxf(num0.x * invd0, 0.f);
    const float ga1 = fmaxf(num0.y * invd0, 0.f);
    const float invd1 = 1.f / den1;
    const float gb0 = fmaxf(num1.x * invd1, 0.f);
    const float gb1 = fmaxf(num1.y * invd1, 0.f);

    float ys0[NS], ys1[NS];
#pragma unroll
    for (int s = 0; s < NS; ++s) {
        const float2 wv = *reinterpret_cast<const float2*>(&WTL[s * NH + o * 2]);
        float p0 = ga0 * wv.x + ga1 * wv.y;
        float p1 = gb0 * wv.x + gb1 * wv.y;
        p0 = row16_allreduce(p0);
        p1 = row16_allreduce(p1);
        ys0[s] = p0 + bL[s];
        ys1[s] = p1 + bL[s];
    }

    if (o == 0) {
        float2* yp0 = reinterpret_cast<float2*>(y + n * NS);
        float2* yp1 = reinterpret_cast<float2*>(y + (n + 32) * NS);
#pragma unroll
        for (int s2 = 0; s2 < 5; ++s2) {
            yp0[s2] = make_float2(ys0[2 * s2], ys0[2 * s2 + 1]);
            yp1[s2] = make_float2(ys1[2 * s2], ys1[2 * s2 + 1]);
        }
    }

    // BN partials: ys uniform per 16-lane group; wave contributes 8 rows
    // (4 groups x 2 row-streams); round-11-verified chain.
#pragma unroll
    for (int s = 0; s < NS; ++s) {
        float v  = uniform16_wavesum_lane63(ys0[s] + ys1[s]);
        float v2 = uniform16_wavesum_lane63(ys0[s] * ys0[s] + ys1[s] * ys1[s]);
        if ((t & 63) == 63) { atomicAdd(&sAcc[s], v); atomicAdd(&sAcc[NS + s], v2); }
    }
    __syncthreads();
    if (t < 2 * NS) {
        if (SLOTS) P[t * NB + blockIdx.x] = sAcc[t];   // plain store, no zeroing
        else       atomicAdd(&P[t], sAcc[t]);          // tiny-ws fallback
    }
}

// ------- BN finalize (160 blocks x 256 threads; NB=256 slot layout) -------
template<bool SLOTS>
__global__ __launch_bounds__(256) void gga_bn(
    float* __restrict__ out, const float* __restrict__ P,
    const float* __restrict__ gamma, const float* __restrict__ beta)
{
    __shared__ float red[2 * NS * 8];
    __shared__ float scL[NS], shL[NS];
    const int t = threadIdx.x;

    if (SLOTS) {
        if (t < 2 * NS * 8) {                      // 160 reducer threads
            const int k = t >> 3, c = t & 7;       // slot row k, chunk c (32 floats)
            const float4* p4 = reinterpret_cast<const float4*>(P + k * NB + c * 32);
            float s = 0.f;
#pragma unroll
            for (int i = 0; i < 8; ++i) {
                float4 v = p4[i];
                s += v.x + v.y + v.z + v.w;
            }
            red[t] = s;
        }
        __syncthreads();
    }
    if (t < NS) {
        float sm, sq;
        if (SLOTS) {
            sm = 0.f; sq = 0.f;
#pragma unroll
            for (int c = 0; c < 8; ++c) {
                sm += red[t * 8 + c];
                sq += red[(NS + t) * 8 + c];
            }
        } else {
            sm = P[t]; sq = P[NS + t];
        }
        const float mu = sm * (1.f / NROWS);
        float var = sq * (1.f / NROWS) - mu * mu;
        var = fmaxf(var, 0.f);
        const float r = rsqrtf(var + BN_EPS);
        scL[t] = gamma[t] * r;
        shL[t] = beta[t] - mu * scL[t];
    }
    __syncthreads();

    const int i4 = (blockIdx.x * 256 + t) * 4;
    float4 v = *reinterpret_cast<const float4*>(out + i4);
    const int s0 = i4 % NS;
    const int s1 = (s0 + 1) % NS, s2 = (s0 + 2) % NS, s3 = (s0 + 3) % NS;
    v.x = fmaf(v.x, scL[s0], shL[s0]);
    v.y = fmaf(v.y, scL[s1], shL[s1]);
    v.z = fmaf(v.z, scL[s2], shL[s2]);
    v.w = fmaf(v.w, scL[s3], shL[s3]);
    *reinterpret_cast<float4*>(out + i4) = v;
}

extern "C" void kernel_launch(void* const* d_in, const int* in_sizes, int n_in,
                              void* d_out, int out_size, void* d_ws, size_t ws_size,
                              hipStream_t stream) {
    const int*   x         = (const int*)d_in[0];
    const float* emb       = (const float*)d_in[1];
    const float* gene_att  = (const float*)d_in[2];
    const float* chrom_att = (const float*)d_in[3];
    const float* W         = (const float*)d_in[4];
    const float* b         = (const float*)d_in[5];
    const float* bn_gamma  = (const float*)d_in[6];
    const float* bn_beta   = (const float*)d_in[7];

    float* y = (float*)d_out;
    float* P = (float*)d_ws;   // SLOTS: P[2*NS][NB] = 20 KB, rewritten every launch

    if (ws_size >= (size_t)(2 * NS * NB * sizeof(float))) {
        gga_main<true><<<NB, BLOCK_A, 0, stream>>>(
            x, emb, gene_att, chrom_att, W, b, y, P);
        gga_bn<true><<<(NROWS * NS) / (256 * 4), 256, 0, stream>>>(
            y, P, bn_gamma, bn_beta);
    } else {
        hipMemsetAsync(P, 0, 2 * NS * sizeof(float), stream);
        gga_main<false><<<NB, BLOCK_A, 0, stream>>>(
            x, emb, gene_att, chrom_att, W, b, y, P);
        gga_bn<false><<<(NROWS * NS) / (256 * 4), 256, 0, stream>>>(
            y, P, bn_gamma, bn_beta);
    }
}

// Round 15
// 22.670 us; speedup vs baseline: 1.9809x; 1.9809x over previous
//
#include <hip/hip_runtime.h>
#include <hip/hip_fp16.h>

#define NROWS 16384
#define NG 100
#define NC 10
#define NH 32
#define NS 10
#define GPC 10
#define SLOPE 0.2f
#define BN_EPS 1e-5f

#define RPB 64             // rows per block
#define BLOCK_A 1024       // 64 rows * 16 lanes/row; ONE row per thread (no spill)
#define NB (NROWS / RPB)   // 256 blocks

// ---- DPP cross-lane adds (VALU pipe; verified rounds 7/8/11/12) ----
template<int CTRL>
__device__ __forceinline__ float dpp_add(float v) {
    int x = __builtin_bit_cast(int, v);
    int y = __builtin_amdgcn_update_dpp(0, x, CTRL, 0xF, 0xF, true);
    return v + __builtin_bit_cast(float, y);
}
__device__ __forceinline__ float row16_allreduce(float v) {
    v = dpp_add<0x128>(v);  // row_ror:8
    v = dpp_add<0x124>(v);  // row_ror:4
    v = dpp_add<0x122>(v);  // row_ror:2
    v = dpp_add<0x121>(v);  // row_ror:1
    return v;
}
// ys UNIFORM within each 16-lane group: lane63 = sum of the wave's 4 groups
__device__ __forceinline__ float uniform16_wavesum_lane63(float v) {
    v = dpp_add<0x142>(v);  // row_bcast15
    v = dpp_add<0x143>(v);  // row_bcast31
    return v;
}

// gather chrom c: ONE ds_read_b64 per gene fetches {h:half2, e:f32}
#define GATHER(c, arr, pkv)                                                \
    _Pragma("unroll")                                                      \
    for (int gp = 0; gp < GPC; ++gp) {                                     \
        const int g_ = (c) * GPC + gp;                                     \
        const unsigned xg_ = (pkv[g_ >> 4] >> ((g_ & 15) * 2)) & 3u;       \
        const int r3_ = g_ * 3 + (int)xg_;                                 \
        arr[gp] = cmbL[r3_ * 16 + o];                                      \
    }

#define COMPUTE(arr, num, den) do {                                        \
    float e_[GPC];                                                         \
    _Pragma("unroll")                                                      \
    for (int gp = 0; gp < GPC; ++gp)                                       \
        e_[gp] = __builtin_bit_cast(float, arr[gp].y);                     \
    const float s01_ = (e_[0] + e_[1]) + (e_[2] + e_[3]);                  \
    const float s23_ = (e_[4] + e_[5]) + (e_[6] + e_[7]);                  \
    const float suma_ = (s01_ + s23_) + (e_[8] + e_[9]);                   \
    const float inv_ = 1.f / fmaxf(suma_, 1e-10f);                         \
    float2 chA_ = {0.f, 0.f}, chB_ = {0.f, 0.f};                           \
    _Pragma("unroll")                                                      \
    for (int gp = 0; gp < GPC; gp += 2) {                                  \
        float2 h0_ = __half22float2(__builtin_bit_cast(__half2, arr[gp].x)); \
        float2 h1_ = __half22float2(__builtin_bit_cast(__half2, arr[gp+1].x)); \
        chA_.x = fmaf(e_[gp],   h0_.x, chA_.x);                            \
        chA_.y = fmaf(e_[gp],   h0_.y, chA_.y);                            \
        chB_.x = fmaf(e_[gp+1], h1_.x, chB_.x);                            \
        chB_.y = fmaf(e_[gp+1], h1_.y, chB_.y);                            \
    }                                                                      \
    float2 ch_ = {chA_.x + chB_.x, chA_.y + chB_.y};                       \
    ch_.x = fmaxf(ch_.x, 0.f);  /* ReLU commutes with +ve 1/suma scale */  \
    ch_.y = fmaxf(ch_.y, 0.f);                                             \
    float pc_ = ch_.x * ca.x + ch_.y * ca.y;                               \
    pc_ = row16_allreduce(pc_);                                            \
    pc_ *= inv_;                       /* catt[n][c] */                    \
    const float lc_ = pc_ > 0.f ? pc_ : SLOPE * pc_;                       \
    const float ec_ = __expf(lc_);                                         \
    const float w_ = ec_ * inv_;                                           \
    num.x = fmaf(w_, ch_.x, num.x);                                        \
    num.y = fmaf(w_, ch_.y, num.y);                                        \
    den += ec_;                                                            \
} while (0)

// ================= main kernel: 256 blocks x 1024 threads, 1 row/thread =====
template<bool SLOTS>
__global__ __launch_bounds__(BLOCK_A, 4) void gga_main(
    const int* __restrict__ x, const float* __restrict__ emb,
    const float* __restrict__ gene_att, const float* __restrict__ chrom_att,
    const float* __restrict__ W, const float* __restrict__ b,
    float* __restrict__ y, float* __restrict__ P)
{
    __shared__ uint2 cmbL[300 * 16];   // 38.4 KB: {x = half2 h(2o,2o+1), y = f32 e}
    __shared__ float eL[300];
    __shared__ float WTL[NS * NH];     // WT[s][h]
    __shared__ float bL[NS];
    __shared__ unsigned xpL[RPB * 8];  // 64 rows * 8 packed words
    __shared__ float sAcc[2 * NS];

    const int t = threadIdx.x;
    const int n0 = blockIdx.x * RPB;

    // ---- phase 0 (round-8 ordering) ----
    if (t < 300) {                                     // e-table from global f32 emb
        const int g = t / 3;
        const float* ga = gene_att + (g / GPC) * NH;
        const float* e = emb + t * NH;
        float s = 0.f;
#pragma unroll
        for (int k = 0; k < NH; k += 4) {
            float4 ev = *reinterpret_cast<const float4*>(e + k);
            float4 gv = *reinterpret_cast<const float4*>(ga + k);
            s = fmaf(gv.x, ev.x, s); s = fmaf(gv.y, ev.y, s);
            s = fmaf(gv.z, ev.z, s); s = fmaf(gv.w, ev.w, s);
        }
        const float lk = s > 0.f ? s : SLOPE * s;
        eL[t] = (s != 0.f) ? __expf(lk) : 0.f;
    }
    if (t < NH * NS) WTL[t] = W[(t & 31) * NS + (t >> 5)];   // WT[s][h]
    if (t < NS) bL[t] = b[t];
    if (t < 2 * NS) sAcc[t] = 0.f;
    if (t < 512) {   // cooperative x pack: 64 rows x 8 words
        const int r = t >> 3, w = t & 7;
        unsigned pw = 0u;
        if (w < 7) {
            const int4* p = reinterpret_cast<const int4*>(x + (n0 + r) * NG + w * 16);
            const int nv = (w < 6) ? 4 : 1;            // word 6: trits 96..99 only
#pragma unroll
            for (int i = 0; i < 4; ++i) {
                if (i < nv) {
                    int4 v = p[i];
                    pw |= ((unsigned)v.x & 3u) << (i * 8 + 0);
                    pw |= ((unsigned)v.y & 3u) << (i * 8 + 2);
                    pw |= ((unsigned)v.z & 3u) << (i * 8 + 4);
                    pw |= ((unsigned)v.w & 3u) << (i * 8 + 6);
                }
            }
        }
        xpL[r * 8 + w] = pw;
    }
    __syncthreads();

    // ---- phase 1: fused {h,e} table (coalesced float2 global reads) ----
#pragma unroll
    for (int i2 = 0; i2 < 5; ++i2) {
        const int i = t + i2 * BLOCK_A;
        if (i < 4800) {                                 // i = r3*16 + o
            float2 hv = reinterpret_cast<const float2*>(emb)[i];
            __half2 h2 = __floats2half2_rn(hv.x, hv.y);
            uint2 en;
            en.x = __builtin_bit_cast(unsigned, h2);
            en.y = __builtin_bit_cast(unsigned, eL[i >> 4]);
            cmbL[i] = en;
        }
    }
    __syncthreads();

    // ---- per-row: 16 lanes/row, lane o owns h comps 2o,2o+1 (round-8 body) ----
    const int lr = t >> 4;          // 0..63
    const int o = t & 15;
    const int n = n0 + lr;

    const float2 ca = reinterpret_cast<const float2*>(chrom_att)[o];

    const uint4 pa = *reinterpret_cast<const uint4*>(&xpL[lr * 8]);
    const uint4 pb = *reinterpret_cast<const uint4*>(&xpL[lr * 8 + 4]);
    const unsigned pk[8] = {pa.x, pa.y, pa.z, pa.w, pb.x, pb.y, pb.z, pb.w};

    float2 num = {0.f, 0.f};
    float den = 0.f;

    // 2-deep software pipeline: gather chrom c+1 while computing chrom c
    uint2 hA[GPC], hB[GPC];
    GATHER(0, hA, pk);
#pragma unroll
    for (int c = 0; c < NC; ++c) {
        if ((c & 1) == 0) { if (c + 1 < NC) { GATHER(c + 1, hB, pk); } COMPUTE(hA, num, den); }
        else              { if (c + 1 < NC) { GATHER(c + 1, hA, pk); } COMPUTE(hB, num, den); }
    }

    const float invd = 1.f / den;
    const float g0 = fmaxf(num.x * invd, 0.f);
    const float g1 = fmaxf(num.y * invd, 0.f);

    float ys[NS];
#pragma unroll
    for (int s = 0; s < NS; ++s) {
        const float2 wv = *reinterpret_cast<const float2*>(&WTL[s * NH + o * 2]);
        float p = g0 * wv.x + g1 * wv.y;
        p = row16_allreduce(p);
        ys[s] = p + bL[s];
    }

    if (o == 0) {
        float2* yp = reinterpret_cast<float2*>(y + n * NS);
#pragma unroll
        for (int s2 = 0; s2 < 5; ++s2) yp[s2] = make_float2(ys[2 * s2], ys[2 * s2 + 1]);
    }

    // BN partials (round-8 semantics: ys uniform per 16-lane group)
#pragma unroll
    for (int s = 0; s < NS; ++s) {
        float v  = uniform16_wavesum_lane63(ys[s]);
        float v2 = uniform16_wavesum_lane63(ys[s] * ys[s]);
        if ((t & 63) == 63) { atomicAdd(&sAcc[s], v); atomicAdd(&sAcc[NS + s], v2); }
    }
    __syncthreads();
    if (t < 2 * NS) {
        if (SLOTS) P[t * NB + blockIdx.x] = sAcc[t];   // plain store, no zeroing
        else       atomicAdd(&P[t], sAcc[t]);          // tiny-ws fallback
    }
}

// ------- BN finalize (160 blocks x 256 threads; NB=256 slot layout) -------
template<bool SLOTS>
__global__ __launch_bounds__(256) void gga_bn(
    float* __restrict__ out, const float* __restrict__ P,
    const float* __restrict__ gamma, const float* __restrict__ beta)
{
    __shared__ float red[2 * NS * 8];
    __shared__ float scL[NS], shL[NS];
    const int t = threadIdx.x;

    if (SLOTS) {
        if (t < 2 * NS * 8) {                      // 160 reducer threads
            const int k = t >> 3, c = t & 7;       // slot row k, chunk c (32 floats)
            const float4* p4 = reinterpret_cast<const float4*>(P + k * NB + c * 32);
            float s = 0.f;
#pragma unroll
            for (int i = 0; i < 8; ++i) {
                float4 v = p4[i];
                s += v.x + v.y + v.z + v.w;
            }
            red[t] = s;
        }
        __syncthreads();
    }
    if (t < NS) {
        float sm, sq;
        if (SLOTS) {
            sm = 0.f; sq = 0.f;
#pragma unroll
            for (int c = 0; c < 8; ++c) {
                sm += red[t * 8 + c];
                sq += red[(NS + t) * 8 + c];
            }
        } else {
            sm = P[t]; sq = P[NS + t];
        }
        const float mu = sm * (1.f / NROWS);
        float var = sq * (1.f / NROWS) - mu * mu;
        var = fmaxf(var, 0.f);
        const float r = rsqrtf(var + BN_EPS);
        scL[t] = gamma[t] * r;
        shL[t] = beta[t] - mu * scL[t];
    }
    __syncthreads();

    const int i4 = (blockIdx.x * 256 + t) * 4;
    float4 v = *reinterpret_cast<const float4*>(out + i4);
    const int s0 = i4 % NS;
    const int s1 = (s0 + 1) % NS, s2 = (s0 + 2) % NS, s3 = (s0 + 3) % NS;
    v.x = fmaf(v.x, scL[s0], shL[s0]);
    v.y = fmaf(v.y, scL[s1], shL[s1]);
    v.z = fmaf(v.z, scL[s2], shL[s2]);
    v.w = fmaf(v.w, scL[s3], shL[s3]);
    *reinterpret_cast<float4*>(out + i4) = v;
}

extern "C" void kernel_launch(void* const* d_in, const int* in_sizes, int n_in,
                              void* d_out, int out_size, void* d_ws, size_t ws_size,
                              hipStream_t stream) {
    const int*   x         = (const int*)d_in[0];
    const float* emb       = (const float*)d_in[1];
    const float* gene_att  = (const float*)d_in[2];
    const float* chrom_att = (const float*)d_in[3];
    const float* W         = (const float*)d_in[4];
    const float* b         = (const float*)d_in[5];
    const float* bn_gamma  = (const float*)d_in[6];
    const float* bn_beta   = (const float*)d_in[7];

    float* y = (float*)d_out;
    float* P = (float*)d_ws;   // SLOTS: P[2*NS][NB] = 20 KB, rewritten every launch

    if (ws_size >= (size_t)(2 * NS * NB * sizeof(float))) {
        gga_main<true><<<NB, BLOCK_A, 0, stream>>>(
            x, emb, gene_att, chrom_att, W, b, y, P);
        gga_bn<true><<<(NROWS * NS) / (256 * 4), 256, 0, stream>>>(
            y, P, bn_gamma, bn_beta);
    } else {
        hipMemsetAsync(P, 0, 2 * NS * sizeof(float), stream);
        gga_main<false><<<NB, BLOCK_A, 0, stream>>>(
            x, emb, gene_att, chrom_att, W, b, y, P);
        gga_bn<false><<<(NROWS * NS) / (256 * 4), 256, 0, stream>>>(
            y, P, bn_gamma, bn_beta);
    }
}